// Round 9
// baseline (896.312 us; speedup 1.0000x reference)
//
#include <hip/hip_runtime.h>

typedef unsigned short u16;
typedef unsigned int u32;
typedef __attribute__((ext_vector_type(8))) short short8v;
typedef __attribute__((ext_vector_type(4))) float f32x4;

#define GLD_LDS(g, l) __builtin_amdgcn_global_load_lds( \
    (const __attribute__((address_space(1))) void*)(g), \
    (__attribute__((address_space(3))) void*)(l), 16, 0, 0)

#define LOG2E 1.44269504f

__device__ __forceinline__ u16 f2bf(float f){
  union { float f; u32 u; } v; v.f = f;
  u32 r = v.u + 0x7FFFu + ((v.u >> 16) & 1u);
  return (u16)(r >> 16);
}
__device__ __forceinline__ float bf2f(u16 h){
  union { u32 u; float f; } v; v.u = ((u32)h) << 16;
  return v.f;
}
__device__ __forceinline__ u32 pk2(float a, float b){
  union { float f; u32 u; } x, y; x.f = a; y.f = b;
  return __builtin_amdgcn_perm(y.u + 0x8000u, x.u + 0x8000u, 0x07060302u);
}
__device__ __forceinline__ float sigm(float x){ return 1.f/(1.f+__expf(-x)); }
__device__ __forceinline__ float tanh_fast(float x){ return 1.f - 2.f/(1.f+__expf(2.f*x)); }

// ---------------------------------------------------------------------------
// prep: all weight matrices -> MFMA B-fragment layout, bf16, zero-padded.
// frag order: (((nt*KC+kc)*4+qd)*16+ln)*8+j  <->  W[g=nt*16+ln][k=kc*32+qd*8+j]
__global__ void prep_kernel(const float* dih, const float* dhh,
    const float* eih, const float* ehh, const float* wq, const float* wk, const float* wv,
    u16* Dih, u16* Dhh, u16* Eih, u16* Ehh, u16* Qf, u16* Kf, u16* Vf)
{
  int idx = blockIdx.x*256 + threadIdx.x;
  const float* src; u16* dst; int KC, Kc, e;
  if      (idx < 27648){ src=dih; dst=Dih; KC=3; Kc=96; e=idx; }
  else if (idx < 55296){ src=dhh; dst=Dhh; KC=3; Kc=96; e=idx-27648; }
  else if (idx < 64512){ src=eih; dst=Eih; KC=2; Kc=48; e=idx-55296; }
  else if (idx < 73728){ src=ehh; dst=Ehh; KC=2; Kc=48; e=idx-64512; }
  else if (idx < 76800){ src=wq;  dst=Qf;  KC=2; Kc=48; e=idx-73728; }
  else if (idx < 79872){ src=wk;  dst=Kf;  KC=2; Kc=48; e=idx-76800; }
  else if (idx < 82944){ src=wv;  dst=Vf;  KC=2; Kc=48; e=idx-79872; }
  else return;
  int j = e & 7, ln = (e>>3) & 15, qd = (e>>7) & 3, tkc = e>>9;
  int kc = tkc % KC, nt = tkc / KC;
  int g = nt*16 + ln, k = kc*32 + qd*8 + j;
  dst[e] = (k < Kc) ? f2bf(src[g*Kc + k]) : (u16)0;
}

// ---------------------------------------------------------------------------
// setup: KV projection (blocks 0..503) + encoder (504..511). Weight frags
// come pre-built from prep (coalesced GLD_LDS staging). K/V written via
// LDS-transposed coalesced stores.
__global__ __launch_bounds__(256) void setup_kernel(
    const float* past, const float* conv_w, const float* conv_b,
    const float* enc_b_ih, const float* enc_b_hh,
    const float* memory_past, const float* memory_fut,
    const float* bq, const float* bk, const float* bv,
    const u16* EihF, const u16* EhhF, const u16* WqF, const u16* WkF, const u16* WvF,
    float* stateP, float* qf, u16* qbB, u16* Kb, u16* Vc)
{
  __shared__ __align__(16) char SMEM[61440];
  const int tid = threadIdx.x, bx = blockIdx.x;
  const int wid = tid>>6, lane = tid&63, qd = lane>>4, ln = lane&15;
  f32x4 zf = {0.f,0.f,0.f,0.f};

  if (bx >= 504){
    // ======== ENCODER ========
    int eb = bx - 504;
    u16* sWih = (u16*)(SMEM);
    u16* sWhh = (u16*)(SMEM + 18432);
    u16* sWq  = (u16*)(SMEM + 36864);
    float* sCw = (float*)(SMEM + 43008);
    float* sCb = (float*)(SMEM + 44160);
    float* sPast = (float*)(SMEM + 44352);
    u16* sHbW = (u16*)(SMEM + 48448 + wid*2304);
    for (int i = wid; i < 18; i += 4) GLD_LDS((const char*)EihF + i*1024 + lane*16, SMEM + i*1024);
    for (int i = wid; i < 18; i += 4) GLD_LDS((const char*)EhhF + i*1024 + lane*16, SMEM + 18432 + i*1024);
    for (int i = wid; i < 6;  i += 4) GLD_LDS((const char*)WqF  + i*1024 + lane*16, SMEM + 36864 + i*1024);
    for (int i = tid; i < 288; i += 256) sCw[i] = conv_w[i];
    if (tid < 48) sCb[tid] = conv_b[tid];
    for (int i = tid; i < 1024; i += 256) sPast[i] = past[eb*1024 + i];
    __syncthreads();
    short8v aE[8][2];
    {
      const float* pr = &sPast[(wid*16 + ln)*16];
      for (int t = 0; t < 8; ++t)
        for (int kc = 0; kc < 2; ++kc){
          union { short8v v; u16 h[8]; } u;
          #pragma unroll
          for (int j = 0; j < 8; ++j){
            int d = kc*32 + qd*8 + j;
            float a = 0.f;
            if (d < 48){
              a = sCb[d];
              #pragma unroll
              for (int kt = 0; kt < 3; ++kt){
                int tau = t + kt - 1;
                if (tau >= 0 && tau < 8){
                  a += pr[tau*2+0]*sCw[d*6+kt];
                  a += pr[tau*2+1]*sCw[d*6+3+kt];
                }
              }
              a = fmaxf(a, 0.f);
            }
            u.h[j] = (d < 48) ? f2bf(a) : (u16)0;
          }
          aE[t][kc] = u.v;
        }
    }
    for (int i = lane; i < 576; i += 64) ((u32*)sHbW)[i] = 0;
    float biR[3],biZ[3],biN[3],bhR[3],bhZ[3],bhN[3];
    #pragma unroll
    for (int i = 0; i < 3; ++i){
      int d = i*16 + ln;
      biR[i]=enc_b_ih[d]; biZ[i]=enc_b_ih[48+d]; biN[i]=enc_b_ih[96+d];
      bhR[i]=enc_b_hh[d]; bhZ[i]=enc_b_hh[48+d]; bhN[i]=enc_b_hh[96+d];
    }
    float hreg[3][4];
    #pragma unroll
    for (int i=0;i<3;++i) for (int r=0;r<4;++r) hreg[i][r]=0.f;
    int r0 = eb*64 + wid*16;
    #pragma unroll 1
    for (int t = 0; t < 8; ++t){
      short8v aH0 = *(const short8v*)&sHbW[ln*72 + qd*8];
      short8v aH1 = *(const short8v*)&sHbW[ln*72 + 32 + qd*8];
      f32x4 gI[9], gH[9];
      #pragma unroll
      for (int nt = 0; nt < 9; ++nt){ gI[nt] = zf; gH[nt] = zf; }
      #pragma unroll
      for (int nt = 0; nt < 9; ++nt){
        gI[nt] = __builtin_amdgcn_mfma_f32_16x16x32_bf16(aE[t][0], *(const short8v*)&sWih[((nt*2+0)*4+qd)*128 + ln*8], gI[nt], 0,0,0);
        gI[nt] = __builtin_amdgcn_mfma_f32_16x16x32_bf16(aE[t][1], *(const short8v*)&sWih[((nt*2+1)*4+qd)*128 + ln*8], gI[nt], 0,0,0);
        gH[nt] = __builtin_amdgcn_mfma_f32_16x16x32_bf16(aH0, *(const short8v*)&sWhh[((nt*2+0)*4+qd)*128 + ln*8], gH[nt], 0,0,0);
        gH[nt] = __builtin_amdgcn_mfma_f32_16x16x32_bf16(aH1, *(const short8v*)&sWhh[((nt*2+1)*4+qd)*128 + ln*8], gH[nt], 0,0,0);
      }
      #pragma unroll
      for (int i3 = 0; i3 < 3; ++i3)
        #pragma unroll
        for (int r = 0; r < 4; ++r){
          float rr = sigm(gI[i3][r]+biR[i3] + gH[i3][r]+bhR[i3]);
          float zz = sigm(gI[i3+3][r]+biZ[i3] + gH[i3+3][r]+bhZ[i3]);
          float nn = tanh_fast(gI[i3+6][r]+biN[i3] + rr*(gH[i3+6][r]+bhN[i3]));
          float hv = (1.f-zz)*nn + zz*hreg[i3][r];
          hreg[i3][r] = hv;
          sHbW[(qd*4+r)*72 + i3*16 + ln] = f2bf(hv);
        }
    }
    #pragma unroll
    for (int i3 = 0; i3 < 3; ++i3)
      #pragma unroll
      for (int r = 0; r < 4; ++r)
        stateP[(r0+qd*4+r)*48 + i3*16 + ln] = hreg[i3][r];
    short8v aH0 = *(const short8v*)&sHbW[ln*72 + qd*8];
    short8v aH1 = *(const short8v*)&sHbW[ln*72 + 32 + qd*8];
    f32x4 q3[3];
    #pragma unroll
    for (int nt = 0; nt < 3; ++nt){
      q3[nt] = zf;
      q3[nt] = __builtin_amdgcn_mfma_f32_16x16x32_bf16(aH0, *(const short8v*)&sWq[((nt*2+0)*4+qd)*128 + ln*8], q3[nt], 0,0,0);
      q3[nt] = __builtin_amdgcn_mfma_f32_16x16x32_bf16(aH1, *(const short8v*)&sWq[((nt*2+1)*4+qd)*128 + ln*8], q3[nt], 0,0,0);
    }
    #pragma unroll
    for (int nt = 0; nt < 3; ++nt)
      #pragma unroll
      for (int r = 0; r < 4; ++r){
        int row = r0 + qd*4 + r, d = nt*16 + ln;
        float v = q3[nt][r] + bq[d];
        qf[row*48 + d] = v;
        qbB[row*64 + d] = f2bf(v * LOG2E);
      }
    #pragma unroll
    for (int r = 0; r < 4; ++r)
      if (ln < 8) *(u32*)&qbB[(r0+qd*4+r)*64 + 48 + ln*2] = 0;
  } else {
    // ======== KV projection (tile = 64 keys per block pass) ========
    u16* sWkF = (u16*)(SMEM);                         // 6144 B
    u16* sWvF = (u16*)(SMEM + 6144);                  // 6144 B
    u16* smp  = (u16*)(SMEM + 12288 + wid*2304);
    u16* smf  = (u16*)(SMEM + 21504 + wid*2304);
    u16* sKT  = (u16*)(SMEM + 30720);                 // 64x64 u16 = 8192 B
    u16* sVT  = (u16*)(SMEM + 38912);                 // 48x72 u16 = 6912 B
    for (int i = wid; i < 6; i += 4) GLD_LDS((const char*)WkF + i*1024 + lane*16, SMEM + i*1024);
    for (int i = wid; i < 6; i += 4) GLD_LDS((const char*)WvF + i*1024 + lane*16, SMEM + 6144 + i*1024);
    float bkv[3], bvv[3];
    #pragma unroll
    for (int nt = 0; nt < 3; ++nt){ bkv[nt] = bk[nt*16+ln]; bvv[nt] = bv[nt*16+ln]; }
    int ntile = (bx < 8) ? 2 : 1;
    for (int tt = 0; tt < ntile; ++tt){
      int tile = (tt == 0) ? bx : (504 + bx);
      int r0 = tile*64 + wid*16;
      for (int i = lane; i < 576; i += 64){ ((u32*)smp)[i] = 0; ((u32*)smf)[i] = 0; }
      for (int i = lane; i < 768; i += 64){
        int r = i/48, c = i - r*48;
        smp[r*72+c] = f2bf(memory_past[(size_t)r0*48 + i]);
        smf[r*72+c] = f2bf(memory_fut[(size_t)r0*48 + i]);
      }
      __syncthreads();   // also covers GLD_LDS weight staging on first tile
      short8v aP0 = *(const short8v*)&smp[ln*72 + qd*8];
      short8v aP1 = *(const short8v*)&smp[ln*72 + 32 + qd*8];
      short8v aF0 = *(const short8v*)&smf[ln*72 + qd*8];
      short8v aF1 = *(const short8v*)&smf[ln*72 + 32 + qd*8];
      f32x4 k3[3], v3[3];
      #pragma unroll
      for (int nt = 0; nt < 3; ++nt){ k3[nt] = zf; v3[nt] = zf; }
      #pragma unroll
      for (int nt = 0; nt < 3; ++nt){
        k3[nt] = __builtin_amdgcn_mfma_f32_16x16x32_bf16(aP0, *(const short8v*)&sWkF[((nt*2+0)*4+qd)*128 + ln*8], k3[nt], 0,0,0);
        k3[nt] = __builtin_amdgcn_mfma_f32_16x16x32_bf16(aP1, *(const short8v*)&sWkF[((nt*2+1)*4+qd)*128 + ln*8], k3[nt], 0,0,0);
        v3[nt] = __builtin_amdgcn_mfma_f32_16x16x32_bf16(aF0, *(const short8v*)&sWvF[((nt*2+0)*4+qd)*128 + ln*8], v3[nt], 0,0,0);
        v3[nt] = __builtin_amdgcn_mfma_f32_16x16x32_bf16(aF1, *(const short8v*)&sWvF[((nt*2+1)*4+qd)*128 + ln*8], v3[nt], 0,0,0);
      }
      // scatter into LDS tiles (bank-benign), zero-pad K cols 48..63
      for (int i = lane; i < 128; i += 64) ((u32*)sKT)[(wid*16 + (i>>3))*32 + 24 + (i&7)] = 0;
      #pragma unroll
      for (int nt = 0; nt < 3; ++nt)
        #pragma unroll
        for (int r = 0; r < 4; ++r){
          int keyl = wid*16 + qd*4 + r, d = nt*16 + ln;
          sKT[keyl*64 + d] = f2bf(k3[nt][r] + bkv[nt]);
          sVT[d*72 + keyl] = f2bf(v3[nt][r] + bvv[nt]);
        }
      __syncthreads();
      // coalesced writeback: K 8KB contiguous; V rows of 128B
      for (int i = tid; i < 512; i += 256)
        *(uint4*)((char*)(Kb + (size_t)tile*64*64) + i*16) = *(const uint4*)((char*)sKT + i*16);
      for (int i = tid; i < 384; i += 256){
        int d = i>>3, sub = i&7;
        *(uint4*)((char*)(Vc + ((size_t)((tile*64)>>8)*48 + d)*256 + ((tile*64)&255)) + sub*16)
            = *(const uint4*)((char*)sVT + d*144 + sub*16);
      }
      __syncthreads();
    }
  }
}

// ---------------------------------------------------------------------------
// iter: [combine prev -> pred/q] + [flash partials cur].
// grid 512 = 32 rowgroups(16 rows) x 16 chunks(2048 keys); wave = 16 rows x 512 keys.
// partial layout: a[(ch*512 + row)*48 + d]  (slab-contiguous per chunk)
__global__ __launch_bounds__(256, 2) void iter_kernel(int mode, int it,
    const u16* qbB, const u16* Kb, const u16* Vc, const u16* WqF, const float* bq,
    const float* qfP, float* qfC, float* pred,
    const float* mP, const float* lP, const float* aP,
    float* mC, float* lC, float* aC)
{
  // LDS: [0,12800) union{ sp 4x2304 | sMg 4x16x50x4 } ; 12800 sQ(2048);
  // 14848 sWc(1024); 15872 sLg(64); 15936 sCb(2304) -> 18240
  __shared__ __align__(16) char SMEM[18240];
  u16*   sQ  = (u16*)(SMEM + 12800);
  float* sWc = (float*)(SMEM + 14848);
  float* sLg = (float*)(SMEM + 15872);
  u16*   sCb = (u16*)(SMEM + 15936);
  const int tid = threadIdx.x, bx = blockIdx.x;
  const int wid = tid>>6, lane = tid&63, qd = lane>>4, ln = lane&15;
  const int rg = bx>>4, ch = bx&15;
  const int rowbase = rg*16;
  f32x4 zf = {0.f,0.f,0.f,0.f};

  if (mode == 1){
    // ---- Phase A: softmax-combine weights ----
    {
      int row = tid>>4, j = tid&15, grow = rowbase + row;
      float m = mP[grow*16 + j], l = lP[grow*16 + j];
      float mg = m;
      #pragma unroll
      for (int k = 1; k < 16; k <<= 1) mg = fmaxf(mg, __shfl_xor(mg, k));
      float w = exp2f(m - mg), wl = w*l;
      #pragma unroll
      for (int k = 1; k < 16; k <<= 1) wl += __shfl_xor(wl, k);
      sWc[row*16 + j] = w;
      if (j == 0) sLg[row] = wl;
    }
    __syncthreads();
    // ---- Phase B: per-wave weighted accumulation (rows wid*4..+4, f32x2 granules) ----
    {
      int idx0 = lane, idx1 = 64 + lane;
      int r0l = wid*4 + idx0/24, d0 = (idx0%24)*2;
      int r1l = wid*4 + idx1/24, d1 = (idx1%24)*2;
      float2 a0 = {0.f,0.f}, a1 = {0.f,0.f};
      #pragma unroll
      for (int c = 0; c < 16; ++c){
        const float2* slab = (const float2*)(aP + ((size_t)c*512 + rowbase + wid*4)*48);
        float2 v0 = slab[idx0];
        float w0 = sWc[r0l*16 + c];
        a0.x += w0*v0.x; a0.y += w0*v0.y;
        if (lane < 32){
          float2 v1 = slab[idx1];
          float w1 = sWc[r1l*16 + c];
          a1.x += w1*v1.x; a1.y += w1*v1.y;
        }
      }
      {
        float lg = sLg[r0l];
        float ax = a0.x/lg, ay = a0.y/lg;
        int grow = rowbase + r0l;
        if (ch == 0){ float2 pv = {ax, ay}; *(float2*)&pred[((size_t)grow*20 + (it-1))*48 + d0] = pv; }
        float2 qv = *(const float2*)&qfP[grow*48 + d0];
        *(u32*)&sCb[r0l*72 + d0] = pk2(qv.x + ax, qv.y + ay);
      }
      if (lane < 32){
        float lg = sLg[r1l];
        float ax = a1.x/lg, ay = a1.y/lg;
        int grow = rowbase + r1l;
        if (ch == 0){ float2 pv = {ax, ay}; *(float2*)&pred[((size_t)grow*20 + (it-1))*48 + d1] = pv; }
        float2 qv = *(const float2*)&qfP[grow*48 + d1];
        *(u32*)&sCb[r1l*72 + d1] = pk2(qv.x + ax, qv.y + ay);
      }
    }
    if (tid < 128){ int r2 = tid>>3, p = tid&7; ((u32*)&sCb[r2*72 + 48])[p] = 0; }
    __syncthreads();
    // ---- q projection (wave 0); sQ pad (wave 1) ----
    if (wid == 0){
      short8v ac0 = *(const short8v*)&sCb[ln*72 + qd*8];
      short8v ac1 = *(const short8v*)&sCb[ln*72 + 32 + qd*8];
      f32x4 q3[3];
      #pragma unroll
      for (int nt = 0; nt < 3; ++nt){
        q3[nt] = zf;
        q3[nt] = __builtin_amdgcn_mfma_f32_16x16x32_bf16(ac0, *(const short8v*)&WqF[((nt*2+0)*4+qd)*128 + ln*8], q3[nt], 0,0,0);
        q3[nt] = __builtin_amdgcn_mfma_f32_16x16x32_bf16(ac1, *(const short8v*)&WqF[((nt*2+1)*4+qd)*128 + ln*8], q3[nt], 0,0,0);
      }
      #pragma unroll
      for (int nt = 0; nt < 3; ++nt)
        #pragma unroll
        for (int r = 0; r < 4; ++r){
          int lr = qd*4 + r, d = nt*16 + ln;
          float v = q3[nt][r] + bq[d];
          if (ch == 0) qfC[(rowbase + lr)*48 + d] = v;
          sQ[lr*64 + d] = f2bf(v * LOG2E);
        }
    } else if (wid == 1){
      for (int i = lane; i < 128; i += 64)
        ((u32*)sQ)[(i>>3)*32 + 24 + (i&7)] = 0;
    }
    __syncthreads();
  } else {
    const u32* src = (const u32*)(qbB + rowbase*64);
    ((u32*)sQ)[tid] = src[tid];
    ((u32*)sQ)[256 + tid] = src[256 + tid];
    __syncthreads();
  }

  // ---- flash: wave = 16 rows x 512 keys (8 kt of 64) ----
  u16* sp = (u16*)SMEM + wid*1152;
  short8v aq0 = *(const short8v*)&sQ[ln*64 + qd*8];
  short8v aq1 = *(const short8v*)&sQ[ln*64 + 32 + qd*8];
  f32x4 acc[3] = {zf, zf, zf};
  float mrun = -3.0e38f, lrun = 0.f;
  const int wslice = ch*2048 + wid*512;
  #pragma unroll
  for (int kt = 0; kt < 8; ++kt){
    const int tb = wslice + kt*64;
    const u16* kb = Kb + (size_t)tb*64;
    const u16* vb = Vc + (size_t)(tb>>8)*48*256 + (tb & 255);
    short8v kf[4][2], vf[2][3];
    #pragma unroll
    for (int nt = 0; nt < 4; ++nt)
      #pragma unroll
      for (int kc = 0; kc < 2; ++kc)
        kf[nt][kc] = *(const short8v*)&kb[(nt*16+ln)*64 + kc*32 + qd*8];
    #pragma unroll
    for (int kc = 0; kc < 2; ++kc)
      #pragma unroll
      for (int dt = 0; dt < 3; ++dt)
        vf[kc][dt] = *(const short8v*)&vb[(dt*16+ln)*256 + kc*32 + qd*8];
    f32x4 s[4];
    #pragma unroll
    for (int nt = 0; nt < 4; ++nt){
      f32x4 z = zf;
      z = __builtin_amdgcn_mfma_f32_16x16x32_bf16(kf[nt][0], aq0, z, 0,0,0);
      z = __builtin_amdgcn_mfma_f32_16x16x32_bf16(kf[nt][1], aq1, z, 0,0,0);
      s[nt] = z;
    }
    float vmax = s[0][0];
    #pragma unroll
    for (int nt = 0; nt < 4; ++nt)
      #pragma unroll
      for (int r = 0; r < 4; ++r) vmax = fmaxf(vmax, s[nt][r]);
    vmax = fmaxf(vmax, __shfl_xor(vmax, 16));
    vmax = fmaxf(vmax, __shfl_xor(vmax, 32));
    float mnew = fmaxf(mrun, vmax);
    float alpha = exp2f(mrun - mnew);
    mrun = mnew;
    float lsum = 0.f;
    #pragma unroll
    for (int nt = 0; nt < 4; ++nt){
      float p0 = exp2f(s[nt][0]-mnew), p1 = exp2f(s[nt][1]-mnew);
      float p2 = exp2f(s[nt][2]-mnew), p3 = exp2f(s[nt][3]-mnew);
      lsum += (p0+p1)+(p2+p3);
      uint2 pk; pk.x = pk2(p0,p1); pk.y = pk2(p2,p3);
      *(uint2*)&sp[ln*72 + nt*16 + qd*4] = pk;
    }
    lsum += __shfl_xor(lsum, 16);
    lsum += __shfl_xor(lsum, 32);
    lrun = lrun*alpha + lsum;
    #pragma unroll
    for (int dt = 0; dt < 3; ++dt){
      acc[dt][0] *= alpha; acc[dt][1] *= alpha;
      acc[dt][2] *= alpha; acc[dt][3] *= alpha;
    }
    short8v pb0 = *(const short8v*)&sp[ln*72 + qd*8];
    short8v pb1 = *(const short8v*)&sp[ln*72 + 32 + qd*8];
    #pragma unroll
    for (int dt = 0; dt < 3; ++dt){
      acc[dt] = __builtin_amdgcn_mfma_f32_16x16x32_bf16(vf[0][dt], pb0, acc[dt], 0,0,0);
      acc[dt] = __builtin_amdgcn_mfma_f32_16x16x32_bf16(vf[1][dt], pb1, acc[dt], 0,0,0);
    }
  }
  // ---- 4-wave merge -> one partial per (row, chunk), slab layout ----
  __syncthreads();
  float* sMg = (float*)SMEM;   // aliases sp (dead)
  #pragma unroll
  for (int dt = 0; dt < 3; ++dt)
    #pragma unroll
    for (int r = 0; r < 4; ++r)
      sMg[wid*800 + ln*50 + dt*16 + qd*4 + r] = acc[dt][r];
  if (lane < 16){ sMg[wid*800 + ln*50 + 48] = mrun; sMg[wid*800 + ln*50 + 49] = lrun; }
  __syncthreads();
  if (tid < 128){
    int row = tid>>3, jj = tid&7, grow = rowbase + row;
    float m0 = sMg[row*50+48], m1 = sMg[800+row*50+48];
    float m2 = sMg[1600+row*50+48], m3 = sMg[2400+row*50+48];
    float mg = fmaxf(fmaxf(m0,m1), fmaxf(m2,m3));
    float e0 = exp2f(m0-mg), e1 = exp2f(m1-mg), e2 = exp2f(m2-mg), e3 = exp2f(m3-mg);
    float lg = e0*sMg[row*50+49] + e1*sMg[800+row*50+49]
             + e2*sMg[1600+row*50+49] + e3*sMg[2400+row*50+49];
    if (jj == 0){ mC[grow*16 + ch] = mg; lC[grow*16 + ch] = lg; }
    int d0 = jj*6;
    #pragma unroll
    for (int d6 = 0; d6 < 6; ++d6){
      int d = d0 + d6;
      aC[((size_t)ch*512 + grow)*48 + d] =
          e0*sMg[row*50+d] + e1*sMg[800+row*50+d]
        + e2*sMg[1600+row*50+d] + e3*sMg[2400+row*50+d];
    }
  }
}

// ---------------------------------------------------------------------------
// decoder: 12-step GRU(96); 640 blocks x 192 thr; gates 3-way wave split;
// Dhh fragments in VGPRs across all steps; inline j==19 combine.
__global__ __launch_bounds__(192) void dec_kernel(
    const u16* Dihf, const u16* Dhhf, const float* b_ih, const float* b_hh,
    const float* stateP, const float* pred, const float* obs,
    const float* mF, const float* lF, const float* aF,
    const float* fc_w, const float* fc_b, float* out)
{
  __shared__ __align__(16) u16 sx[2][16*104];
  __shared__ float sPx[2][3][16], sPy[2][3][16];
  const int tid = threadIdx.x, bx = blockIdx.x;
  const int wid = tid/64, lane = tid%64, qd = (lane>>4), ln = lane&15;
  const int rw = bx*16;
  f32x4 zf = {0.f,0.f,0.f,0.f};

  for (int i = tid; i < 1536; i += 192){
    int r = i/96, k = i - r*96;
    int row = rw + r, b20 = row/20;
    float v = (k < 48) ? stateP[b20*48 + k] : pred[(size_t)row*48 + (k-48)];
    sx[0][r*104 + k] = f2bf(v);
  }
  if (tid < 48){
    int r19 = (19 - (rw % 20)) % 20;
    if (r19 < 16){
      int b = (rw + r19)/20;
      float mg = -3.0e38f, mv[16];
      #pragma unroll
      for (int c = 0; c < 16; ++c){ mv[c] = mF[b*16 + c]; mg = fmaxf(mg, mv[c]); }
      float num = 0.f, den = 0.f;
      #pragma unroll
      for (int c = 0; c < 16; ++c){
        float w = exp2f(mv[c] - mg);
        den += w * lF[b*16 + c];
        num += w * aF[((size_t)c*512 + b)*48 + tid];
      }
      sx[0][r19*104 + 48 + tid] = f2bf(num/den);
    }
  }
  short8v whh[6][3];
  #pragma unroll
  for (int g = 0; g < 3; ++g)
    #pragma unroll
    for (int u = 0; u < 2; ++u){
      int nt = g*6 + wid*2 + u;
      #pragma unroll
      for (int kc = 0; kc < 3; ++kc)
        whh[g*2+u][kc] = *(const short8v*)&Dhhf[((nt*3+kc)*4+qd)*128 + ln*8];
    }
  float biR[2],biZ[2],biN[2],bhR[2],bhZ[2],bhN[2],fw0[2],fw1[2];
  #pragma unroll
  for (int u = 0; u < 2; ++u){
    int d = (wid*2+u)*16 + ln;
    biR[u]=b_ih[d]; biZ[u]=b_ih[96+d]; biN[u]=b_ih[192+d];
    bhR[u]=b_hh[d]; bhZ[u]=b_hh[96+d]; bhN[u]=b_hh[192+d];
    fw0[u]=fc_w[d]; fw1[u]=fc_w[96+d];
  }
  float hold[2][4];
  #pragma unroll
  for (int u = 0; u < 2; ++u) for (int r = 0; r < 4; ++r) hold[u][r] = 0.f;
  float fcb0 = fc_b[0], fcb1 = fc_b[1];
  float pres0 = 0.f, pres1 = 0.f;
  if (wid == 0 && lane < 16){
    int b20 = (rw + lane)/20;
    pres0 = obs[b20*16 + 14];
    pres1 = obs[b20*16 + 15];
  }
  __syncthreads();

  #pragma unroll 1
  for (int t = 0; t < 12; ++t){
    const u16* sr = sx[t&1];
    u16* sw = sx[(t+1)&1];
    short8v xa0 = *(const short8v*)&sr[ln*104 + qd*8];
    short8v xa1 = *(const short8v*)&sr[ln*104 + 32 + qd*8];
    short8v xa2 = *(const short8v*)&sr[ln*104 + 64 + qd*8];
    f32x4 acc[6];
    #pragma unroll
    for (int i = 0; i < 6; ++i) acc[i] = zf;
    if (t == 0){
      #pragma unroll
      for (int j6 = 0; j6 < 6; ++j6){
        int nt = (j6>>1)*6 + wid*2 + (j6&1);
        acc[j6] = __builtin_amdgcn_mfma_f32_16x16x32_bf16(xa0, *(const short8v*)&Dihf[((nt*3+0)*4+qd)*128 + ln*8], acc[j6], 0,0,0);
        acc[j6] = __builtin_amdgcn_mfma_f32_16x16x32_bf16(xa1, *(const short8v*)&Dihf[((nt*3+1)*4+qd)*128 + ln*8], acc[j6], 0,0,0);
        acc[j6] = __builtin_amdgcn_mfma_f32_16x16x32_bf16(xa2, *(const short8v*)&Dihf[((nt*3+2)*4+qd)*128 + ln*8], acc[j6], 0,0,0);
      }
    } else {
      #pragma unroll
      for (int j6 = 0; j6 < 6; ++j6){
        acc[j6] = __builtin_amdgcn_mfma_f32_16x16x32_bf16(xa0, whh[j6][0], acc[j6], 0,0,0);
        acc[j6] = __builtin_amdgcn_mfma_f32_16x16x32_bf16(xa1, whh[j6][1], acc[j6], 0,0,0);
        acc[j6] = __builtin_amdgcn_mfma_f32_16x16x32_bf16(xa2, whh[j6][2], acc[j6], 0,0,0);
      }
    }
    float px[4] = {0,0,0,0}, py[4] = {0,0,0,0};
    #pragma unroll
    for (int r = 0; r < 4; ++r)
      #pragma unroll
      for (int u = 0; u < 2; ++u){
        float rr = sigm(acc[0+u][r] + biR[u] + bhR[u]);
        float zz = sigm(acc[2+u][r] + biZ[u] + bhZ[u]);
        float nn = (t == 0) ? tanh_fast(acc[4+u][r] + biN[u] + rr*bhN[u])
                            : tanh_fast(biN[u] + rr*(acc[4+u][r] + bhN[u]));
        float hv = (1.f-zz)*nn + zz*hold[u][r];
        hold[u][r] = hv;
        sw[(qd*4+r)*104 + (wid*2+u)*16 + ln] = f2bf(hv);
        px[r] += fw0[u]*hv;
        py[r] += fw1[u]*hv;
      }
    #pragma unroll
    for (int msk = 8; msk >= 1; msk >>= 1)
      #pragma unroll
      for (int r = 0; r < 4; ++r){
        px[r] += __shfl_xor(px[r], msk);
        py[r] += __shfl_xor(py[r], msk);
      }
    if (ln == 0){
      #pragma unroll
      for (int r = 0; r < 4; ++r){
        sPx[t&1][wid][qd*4+r] = px[r];
        sPy[t&1][wid][qd*4+r] = py[r];
      }
    }
    __syncthreads();
    if (wid == 0 && lane < 16){
      float fx = sPx[t&1][0][lane] + sPx[t&1][1][lane] + sPx[t&1][2][lane];
      float fy = sPy[t&1][0][lane] + sPy[t&1][1][lane] + sPy[t&1][2][lane];
      pres0 += fx + fcb0;
      pres1 += fy + fcb1;
      out[((size_t)(rw + lane)*12 + t)*2 + 0] = pres0;
      out[((size_t)(rw + lane)*12 + t)*2 + 1] = pres1;
    }
  }
}

// ---------------------------------------------------------------------------
extern "C" void kernel_launch(void* const* d_in, const int* in_sizes, int n_in,
                              void* d_out, int out_size, void* d_ws, size_t ws_size,
                              hipStream_t stream)
{
  const float* past        = (const float*)d_in[0];
  const float* obs         = (const float*)d_in[1];
  const float* conv_w      = (const float*)d_in[2];
  const float* conv_b      = (const float*)d_in[3];
  const float* enc_w_ih    = (const float*)d_in[4];
  const float* enc_w_hh    = (const float*)d_in[5];
  const float* enc_b_ih    = (const float*)d_in[6];
  const float* enc_b_hh    = (const float*)d_in[7];
  const float* memory_past = (const float*)d_in[8];
  const float* memory_fut  = (const float*)d_in[9];
  const float* Wq = (const float*)d_in[10];
  const float* bq = (const float*)d_in[11];
  const float* Wk = (const float*)d_in[12];
  const float* bk = (const float*)d_in[13];
  const float* Wv = (const float*)d_in[14];
  const float* bv = (const float*)d_in[15];
  const float* dec_w_ih = (const float*)d_in[16];
  const float* dec_w_hh = (const float*)d_in[17];
  const float* dec_b_ih = (const float*)d_in[18];
  const float* dec_b_hh = (const float*)d_in[19];
  const float* fc_w = (const float*)d_in[20];
  const float* fc_b = (const float*)d_in[21];
  float* out = (float*)d_out;

  char* ws = (char*)d_ws;
  size_t off = 0;
  auto alloc = [&](size_t bytes){ void* p = ws + off; off += (bytes + 255) & ~(size_t)255; return p; };
  float* stateP = (float*)alloc(512*48*4);
  float* qfA    = (float*)alloc(512*48*4);
  float* qfB    = (float*)alloc(512*48*4);
  u16*   qbB    = (u16*)alloc(512*64*2);
  float* mB[2], *lB[2], *aB[2];
  for (int i = 0; i < 2; ++i){
    mB[i] = (float*)alloc(512*16*4);
    lB[i] = (float*)alloc(512*16*4);
    aB[i] = (float*)alloc((size_t)512*16*48*4);
  }
  float* pred = (float*)alloc((size_t)10240*48*4);
  u16*   Kb   = (u16*)alloc((size_t)32768*64*2);
  u16*   Vc   = (u16*)alloc((size_t)32768*48*2);
  u16*   Dihf = (u16*)alloc(27648*2);
  u16*   Dhhf = (u16*)alloc(27648*2);
  u16*   EihF = (u16*)alloc(9216*2);
  u16*   EhhF = (u16*)alloc(9216*2);
  u16*   WqF  = (u16*)alloc(3072*2);
  u16*   WkF  = (u16*)alloc(3072*2);
  u16*   WvF  = (u16*)alloc(3072*2);
  float* qbuf[2] = { qfA, qfB };

  prep_kernel<<<324, 256, 0, stream>>>(dec_w_ih, dec_w_hh, enc_w_ih, enc_w_hh,
                                       Wq, Wk, Wv, Dihf, Dhhf, EihF, EhhF, WqF, WkF, WvF);

  setup_kernel<<<512, 256, 0, stream>>>(
      past, conv_w, conv_b, enc_b_ih, enc_b_hh, memory_past, memory_fut,
      bq, bk, bv, EihF, EhhF, WqF, WkF, WvF,
      stateP, qfA, qbB, Kb, Vc);

  iter_kernel<<<512, 256, 0, stream>>>(0, 0, qbB, Kb, Vc, WqF, bq,
      qfA, qfA, pred, mB[1], lB[1], aB[1], mB[0], lB[0], aB[0]);
  for (int it = 1; it < 20; ++it){
    int pv = (it-1)&1, cu = it&1;
    iter_kernel<<<512, 256, 0, stream>>>(1, it, qbB, Kb, Vc, WqF, bq,
        qbuf[pv], qbuf[cu], pred, mB[pv], lB[pv], aB[pv], mB[cu], lB[cu], aB[cu]);
  }

  // it=19 wrote buffer index 1 -> dec consumes mB[1]/lB[1]/aB[1]
  dec_kernel<<<640, 192, 0, stream>>>(Dihf, Dhhf, dec_b_ih, dec_b_hh,
      stateP, pred, obs, mB[1], lB[1], aB[1], fc_w, fc_b, out);
}

// Round 10
// 626.264 us; speedup vs baseline: 1.4312x; 1.4312x over previous
//
#include <hip/hip_runtime.h>

typedef unsigned short u16;
typedef unsigned int u32;
typedef __attribute__((ext_vector_type(8))) short short8v;
typedef __attribute__((ext_vector_type(4))) float f32x4;

#define GLD_LDS(g, l) __builtin_amdgcn_global_load_lds( \
    (const __attribute__((address_space(1))) void*)(g), \
    (__attribute__((address_space(3))) void*)(l), 16, 0, 0)

#define LOG2E 1.44269504f

__device__ __forceinline__ u16 f2bf(float f){
  union { float f; u32 u; } v; v.f = f;
  u32 r = v.u + 0x7FFFu + ((v.u >> 16) & 1u);
  return (u16)(r >> 16);
}
__device__ __forceinline__ float bf2f(u16 h){
  union { u32 u; float f; } v; v.u = ((u32)h) << 16;
  return v.f;
}
__device__ __forceinline__ u32 pk2(float a, float b){
  union { float f; u32 u; } x, y; x.f = a; y.f = b;
  return __builtin_amdgcn_perm(y.u + 0x8000u, x.u + 0x8000u, 0x07060302u);
}
__device__ __forceinline__ float sigm(float x){ return 1.f/(1.f+__expf(-x)); }
__device__ __forceinline__ float tanh_fast(float x){ return 1.f - 2.f/(1.f+__expf(2.f*x)); }

// ---------------------------------------------------------------------------
// prep: all weight matrices -> MFMA B-fragment layout, bf16, zero-padded.
__global__ void prep_kernel(const float* dih, const float* dhh,
    const float* eih, const float* ehh, const float* wq, const float* wk, const float* wv,
    u16* Dih, u16* Dhh, u16* Eih, u16* Ehh, u16* Qf, u16* Kf, u16* Vf)
{
  int idx = blockIdx.x*256 + threadIdx.x;
  const float* src; u16* dst; int KC, Kc, e;
  if      (idx < 27648){ src=dih; dst=Dih; KC=3; Kc=96; e=idx; }
  else if (idx < 55296){ src=dhh; dst=Dhh; KC=3; Kc=96; e=idx-27648; }
  else if (idx < 64512){ src=eih; dst=Eih; KC=2; Kc=48; e=idx-55296; }
  else if (idx < 73728){ src=ehh; dst=Ehh; KC=2; Kc=48; e=idx-64512; }
  else if (idx < 76800){ src=wq;  dst=Qf;  KC=2; Kc=48; e=idx-73728; }
  else if (idx < 79872){ src=wk;  dst=Kf;  KC=2; Kc=48; e=idx-76800; }
  else if (idx < 82944){ src=wv;  dst=Vf;  KC=2; Kc=48; e=idx-79872; }
  else return;
  int j = e & 7, ln = (e>>3) & 15, qd = (e>>7) & 3, tkc = e>>9;
  int kc = tkc % KC, nt = tkc / KC;
  int g = nt*16 + ln, k = kc*32 + qd*8 + j;
  dst[e] = (k < Kc) ? f2bf(src[g*Kc + k]) : (u16)0;
}

// ---------------------------------------------------------------------------
// setup: KV projection (blocks 0..503) + encoder (504..511).
__global__ __launch_bounds__(256) void setup_kernel(
    const float* past, const float* conv_w, const float* conv_b,
    const float* enc_b_ih, const float* enc_b_hh,
    const float* memory_past, const float* memory_fut,
    const float* bq, const float* bk, const float* bv,
    const u16* EihF, const u16* EhhF, const u16* WqF, const u16* WkF, const u16* WvF,
    float* stateP, float* qf, u16* qbB, u16* Kb, u16* Vc)
{
  __shared__ __align__(16) char SMEM[61440];
  const int tid = threadIdx.x, bx = blockIdx.x;
  const int wid = tid>>6, lane = tid&63, qd = lane>>4, ln = lane&15;
  f32x4 zf = {0.f,0.f,0.f,0.f};

  if (bx >= 504){
    // ======== ENCODER ========
    int eb = bx - 504;
    u16* sWih = (u16*)(SMEM);
    u16* sWhh = (u16*)(SMEM + 18432);
    u16* sWq  = (u16*)(SMEM + 36864);
    float* sCw = (float*)(SMEM + 43008);
    float* sCb = (float*)(SMEM + 44160);
    float* sPast = (float*)(SMEM + 44352);
    u16* sHbW = (u16*)(SMEM + 48448 + wid*2304);
    for (int i = wid; i < 18; i += 4) GLD_LDS((const char*)EihF + i*1024 + lane*16, SMEM + i*1024);
    for (int i = wid; i < 18; i += 4) GLD_LDS((const char*)EhhF + i*1024 + lane*16, SMEM + 18432 + i*1024);
    for (int i = wid; i < 6;  i += 4) GLD_LDS((const char*)WqF  + i*1024 + lane*16, SMEM + 36864 + i*1024);
    for (int i = tid; i < 288; i += 256) sCw[i] = conv_w[i];
    if (tid < 48) sCb[tid] = conv_b[tid];
    for (int i = tid; i < 1024; i += 256) sPast[i] = past[eb*1024 + i];
    __syncthreads();
    short8v aE[8][2];
    {
      const float* pr = &sPast[(wid*16 + ln)*16];
      for (int t = 0; t < 8; ++t)
        for (int kc = 0; kc < 2; ++kc){
          union { short8v v; u16 h[8]; } u;
          #pragma unroll
          for (int j = 0; j < 8; ++j){
            int d = kc*32 + qd*8 + j;
            float a = 0.f;
            if (d < 48){
              a = sCb[d];
              #pragma unroll
              for (int kt = 0; kt < 3; ++kt){
                int tau = t + kt - 1;
                if (tau >= 0 && tau < 8){
                  a += pr[tau*2+0]*sCw[d*6+kt];
                  a += pr[tau*2+1]*sCw[d*6+3+kt];
                }
              }
              a = fmaxf(a, 0.f);
            }
            u.h[j] = (d < 48) ? f2bf(a) : (u16)0;
          }
          aE[t][kc] = u.v;
        }
    }
    for (int i = lane; i < 576; i += 64) ((u32*)sHbW)[i] = 0;
    float biR[3],biZ[3],biN[3],bhR[3],bhZ[3],bhN[3];
    #pragma unroll
    for (int i = 0; i < 3; ++i){
      int d = i*16 + ln;
      biR[i]=enc_b_ih[d]; biZ[i]=enc_b_ih[48+d]; biN[i]=enc_b_ih[96+d];
      bhR[i]=enc_b_hh[d]; bhZ[i]=enc_b_hh[48+d]; bhN[i]=enc_b_hh[96+d];
    }
    float hreg[3][4];
    #pragma unroll
    for (int i=0;i<3;++i) for (int r=0;r<4;++r) hreg[i][r]=0.f;
    int r0 = eb*64 + wid*16;
    #pragma unroll 1
    for (int t = 0; t < 8; ++t){
      short8v aH0 = *(const short8v*)&sHbW[ln*72 + qd*8];
      short8v aH1 = *(const short8v*)&sHbW[ln*72 + 32 + qd*8];
      f32x4 gI[9], gH[9];
      #pragma unroll
      for (int nt = 0; nt < 9; ++nt){ gI[nt] = zf; gH[nt] = zf; }
      #pragma unroll
      for (int nt = 0; nt < 9; ++nt){
        gI[nt] = __builtin_amdgcn_mfma_f32_16x16x32_bf16(aE[t][0], *(const short8v*)&sWih[((nt*2+0)*4+qd)*128 + ln*8], gI[nt], 0,0,0);
        gI[nt] = __builtin_amdgcn_mfma_f32_16x16x32_bf16(aE[t][1], *(const short8v*)&sWih[((nt*2+1)*4+qd)*128 + ln*8], gI[nt], 0,0,0);
        gH[nt] = __builtin_amdgcn_mfma_f32_16x16x32_bf16(aH0, *(const short8v*)&sWhh[((nt*2+0)*4+qd)*128 + ln*8], gH[nt], 0,0,0);
        gH[nt] = __builtin_amdgcn_mfma_f32_16x16x32_bf16(aH1, *(const short8v*)&sWhh[((nt*2+1)*4+qd)*128 + ln*8], gH[nt], 0,0,0);
      }
      #pragma unroll
      for (int i3 = 0; i3 < 3; ++i3)
        #pragma unroll
        for (int r = 0; r < 4; ++r){
          float rr = sigm(gI[i3][r]+biR[i3] + gH[i3][r]+bhR[i3]);
          float zz = sigm(gI[i3+3][r]+biZ[i3] + gH[i3+3][r]+bhZ[i3]);
          float nn = tanh_fast(gI[i3+6][r]+biN[i3] + rr*(gH[i3+6][r]+bhN[i3]));
          float hv = (1.f-zz)*nn + zz*hreg[i3][r];
          hreg[i3][r] = hv;
          sHbW[(qd*4+r)*72 + i3*16 + ln] = f2bf(hv);
        }
    }
    #pragma unroll
    for (int i3 = 0; i3 < 3; ++i3)
      #pragma unroll
      for (int r = 0; r < 4; ++r)
        stateP[(r0+qd*4+r)*48 + i3*16 + ln] = hreg[i3][r];
    short8v aH0 = *(const short8v*)&sHbW[ln*72 + qd*8];
    short8v aH1 = *(const short8v*)&sHbW[ln*72 + 32 + qd*8];
    f32x4 q3[3];
    #pragma unroll
    for (int nt = 0; nt < 3; ++nt){
      q3[nt] = zf;
      q3[nt] = __builtin_amdgcn_mfma_f32_16x16x32_bf16(aH0, *(const short8v*)&sWq[((nt*2+0)*4+qd)*128 + ln*8], q3[nt], 0,0,0);
      q3[nt] = __builtin_amdgcn_mfma_f32_16x16x32_bf16(aH1, *(const short8v*)&sWq[((nt*2+1)*4+qd)*128 + ln*8], q3[nt], 0,0,0);
    }
    #pragma unroll
    for (int nt = 0; nt < 3; ++nt)
      #pragma unroll
      for (int r = 0; r < 4; ++r){
        int row = r0 + qd*4 + r, d = nt*16 + ln;
        float v = q3[nt][r] + bq[d];
        qf[row*48 + d] = v;
        qbB[row*64 + d] = f2bf(v * LOG2E);
      }
    #pragma unroll
    for (int r = 0; r < 4; ++r)
      if (ln < 8) *(u32*)&qbB[(r0+qd*4+r)*64 + 48 + ln*2] = 0;
  } else {
    // ======== KV projection ========
    u16* sWkF = (u16*)(SMEM);
    u16* sWvF = (u16*)(SMEM + 6144);
    u16* smp  = (u16*)(SMEM + 12288 + wid*2304);
    u16* smf  = (u16*)(SMEM + 21504 + wid*2304);
    u16* sKT  = (u16*)(SMEM + 30720);
    u16* sVT  = (u16*)(SMEM + 38912);
    for (int i = wid; i < 6; i += 4) GLD_LDS((const char*)WkF + i*1024 + lane*16, SMEM + i*1024);
    for (int i = wid; i < 6; i += 4) GLD_LDS((const char*)WvF + i*1024 + lane*16, SMEM + 6144 + i*1024);
    float bkv[3], bvv[3];
    #pragma unroll
    for (int nt = 0; nt < 3; ++nt){ bkv[nt] = bk[nt*16+ln]; bvv[nt] = bv[nt*16+ln]; }
    int ntile = (bx < 8) ? 2 : 1;
    for (int tt = 0; tt < ntile; ++tt){
      int tile = (tt == 0) ? bx : (504 + bx);
      int r0 = tile*64 + wid*16;
      for (int i = lane; i < 576; i += 64){ ((u32*)smp)[i] = 0; ((u32*)smf)[i] = 0; }
      for (int i = lane; i < 768; i += 64){
        int r = i/48, c = i - r*48;
        smp[r*72+c] = f2bf(memory_past[(size_t)r0*48 + i]);
        smf[r*72+c] = f2bf(memory_fut[(size_t)r0*48 + i]);
      }
      __syncthreads();
      short8v aP0 = *(const short8v*)&smp[ln*72 + qd*8];
      short8v aP1 = *(const short8v*)&smp[ln*72 + 32 + qd*8];
      short8v aF0 = *(const short8v*)&smf[ln*72 + qd*8];
      short8v aF1 = *(const short8v*)&smf[ln*72 + 32 + qd*8];
      f32x4 k3[3], v3[3];
      #pragma unroll
      for (int nt = 0; nt < 3; ++nt){ k3[nt] = zf; v3[nt] = zf; }
      #pragma unroll
      for (int nt = 0; nt < 3; ++nt){
        k3[nt] = __builtin_amdgcn_mfma_f32_16x16x32_bf16(aP0, *(const short8v*)&sWkF[((nt*2+0)*4+qd)*128 + ln*8], k3[nt], 0,0,0);
        k3[nt] = __builtin_amdgcn_mfma_f32_16x16x32_bf16(aP1, *(const short8v*)&sWkF[((nt*2+1)*4+qd)*128 + ln*8], k3[nt], 0,0,0);
        v3[nt] = __builtin_amdgcn_mfma_f32_16x16x32_bf16(aF0, *(const short8v*)&sWvF[((nt*2+0)*4+qd)*128 + ln*8], v3[nt], 0,0,0);
        v3[nt] = __builtin_amdgcn_mfma_f32_16x16x32_bf16(aF1, *(const short8v*)&sWvF[((nt*2+1)*4+qd)*128 + ln*8], v3[nt], 0,0,0);
      }
      for (int i = lane; i < 128; i += 64) ((u32*)sKT)[(wid*16 + (i>>3))*32 + 24 + (i&7)] = 0;
      #pragma unroll
      for (int nt = 0; nt < 3; ++nt)
        #pragma unroll
        for (int r = 0; r < 4; ++r){
          int keyl = wid*16 + qd*4 + r, d = nt*16 + ln;
          sKT[keyl*64 + d] = f2bf(k3[nt][r] + bkv[nt]);
          sVT[d*72 + keyl] = f2bf(v3[nt][r] + bvv[nt]);
        }
      __syncthreads();
      for (int i = tid; i < 512; i += 256)
        *(uint4*)((char*)(Kb + (size_t)tile*64*64) + i*16) = *(const uint4*)((char*)sKT + i*16);
      for (int i = tid; i < 384; i += 256){
        int d = i>>3, sub = i&7;
        *(uint4*)((char*)(Vc + ((size_t)((tile*64)>>8)*48 + d)*256 + ((tile*64)&255)) + sub*16)
            = *(const uint4*)((char*)sVT + d*144 + sub*16);
      }
      __syncthreads();
    }
  }
}

// ---------------------------------------------------------------------------
// iter: [combine prev -> pred/q] + [flash partials cur].
// grid 256 = 16 rowgroups(32 rows) x 16 chunks(2048 keys); block 512 thr (8 waves);
// wave = 32 rows x 256 keys (4 kt). partial layout: a[(ch*512+row)*48+d].
__global__ __launch_bounds__(512) void iter_kernel(int mode, int it,
    const u16* qbB, const u16* Kb, const u16* Vc, const u16* WqF, const float* bq,
    const float* qfP, float* qfC, float* pred,
    const float* mP, const float* lP, const float* aP,
    float* mC, float* lC, float* aC)
{
  // LDS: [0,51200) union{ sp 8x4608B | sMg 8x1600f | sRed 8x1536f };
  // 51200 sQ(4096); 55296 sWc(2048); 57344 sLg(128); 57472 sCb(4608) -> 62080
  __shared__ __align__(16) char SMEM[62080];
  u16*   sQ  = (u16*)(SMEM + 51200);
  float* sWc = (float*)(SMEM + 55296);
  float* sLg = (float*)(SMEM + 57344);
  u16*   sCb = (u16*)(SMEM + 57472);
  const int tid = threadIdx.x, bx = blockIdx.x;
  const int wid = tid>>6, lane = tid&63, qd = lane>>4, ln = lane&15;
  const int rg = bx>>4, ch = bx&15;
  const int rowbase = rg*32;
  f32x4 zf = {0.f,0.f,0.f,0.f};

  if (mode == 1){
    float* sRed = (float*)SMEM;
    // Phase A: softmax-combine weights (512 thr = 32 rows x 16 chunks)
    {
      int row = tid>>4, j = tid&15, grow = rowbase + row;
      float m = mP[grow*16 + j], l = lP[grow*16 + j];
      float mg = m;
      #pragma unroll
      for (int k = 1; k < 16; k <<= 1) mg = fmaxf(mg, __shfl_xor(mg, k));
      float w = exp2f(m - mg), wl = w*l;
      #pragma unroll
      for (int k = 1; k < 16; k <<= 1) wl += __shfl_xor(wl, k);
      sWc[row*16 + j] = w;
      if (j == 0) sLg[row] = wl;
    }
    __syncthreads();
    // Phase B: per-wave weighted accumulation over 2 chunk slabs (coalesced b128)
    {
      f32x4 accv[6];
      #pragma unroll
      for (int i = 0; i < 6; ++i) accv[i] = zf;
      #pragma unroll
      for (int ci = 0; ci < 2; ++ci){
        int c = wid*2 + ci;
        const f32x4* slab = (const f32x4*)(aP + ((size_t)c*512 + rowbase)*48);
        #pragma unroll
        for (int i = 0; i < 6; ++i){
          f32x4 v = slab[i*64 + lane];
          int rr = (i*64 + lane)/12;
          float w = sWc[rr*16 + c];
          accv[i][0] += w*v[0]; accv[i][1] += w*v[1];
          accv[i][2] += w*v[2]; accv[i][3] += w*v[3];
        }
      }
      float* red = sRed + wid*1536;
      #pragma unroll
      for (int i = 0; i < 6; ++i)
        *(f32x4*)&red[(i*64 + lane)*4] = accv[i];
    }
    __syncthreads();
    // final sum + att + c
    for (int idx = tid; idx < 1536; idx += 512){
      float s = 0.f;
      #pragma unroll
      for (int w = 0; w < 8; ++w) s += sRed[w*1536 + idx];
      int row = idx/48, d = idx - row*48;
      float a = s / sLg[row];
      if (ch == 0) pred[(size_t)((rowbase+row)*20 + (it-1))*48 + d] = a;
      sCb[row*72 + d] = f2bf(qfP[(rowbase+row)*48 + d] + a);
    }
    if (tid < 256){ int r2 = tid>>3, p = tid&7; ((u32*)&sCb[r2*72 + 48])[p] = 0; }
    __syncthreads();
    // q projection (waves 0,1); pad sQ (waves 2,3)
    if (wid < 2){
      short8v ac0 = *(const short8v*)&sCb[(wid*16+ln)*72 + qd*8];
      short8v ac1 = *(const short8v*)&sCb[(wid*16+ln)*72 + 32 + qd*8];
      f32x4 q3[3];
      #pragma unroll
      for (int nt = 0; nt < 3; ++nt){
        q3[nt] = zf;
        q3[nt] = __builtin_amdgcn_mfma_f32_16x16x32_bf16(ac0, *(const short8v*)&WqF[((nt*2+0)*4+qd)*128 + ln*8], q3[nt], 0,0,0);
        q3[nt] = __builtin_amdgcn_mfma_f32_16x16x32_bf16(ac1, *(const short8v*)&WqF[((nt*2+1)*4+qd)*128 + ln*8], q3[nt], 0,0,0);
      }
      #pragma unroll
      for (int nt = 0; nt < 3; ++nt)
        #pragma unroll
        for (int r = 0; r < 4; ++r){
          int lr = wid*16 + qd*4 + r, d = nt*16 + ln;
          float v = q3[nt][r] + bq[d];
          if (ch == 0) qfC[(rowbase + lr)*48 + d] = v;
          sQ[lr*64 + d] = f2bf(v * LOG2E);
        }
    } else if (wid < 4){
      for (int i = tid-128; i < 256; i += 128){
        int r2 = i>>3, p = i&7;
        ((u32*)&sQ[r2*64 + 48])[p] = 0;
      }
    }
    __syncthreads();
  } else {
    const u32* src = (const u32*)(qbB + rowbase*64);
    ((u32*)sQ)[tid] = src[tid];
    ((u32*)sQ)[512 + tid] = src[512 + tid];
    __syncthreads();
  }

  // ---- flash: wave = 32 rows x 256 keys (4 kt of 64) ----
  u16* sp8 = (u16*)SMEM + wid*2304;
  short8v aq[2][2];
  #pragma unroll
  for (int rt = 0; rt < 2; ++rt)
    #pragma unroll
    for (int kc = 0; kc < 2; ++kc)
      aq[rt][kc] = *(const short8v*)&sQ[(rt*16+ln)*64 + kc*32 + qd*8];
  f32x4 acc[2][3];
  #pragma unroll
  for (int rt = 0; rt < 2; ++rt) for (int dt = 0; dt < 3; ++dt) acc[rt][dt] = zf;
  float mrun[2] = {-3.0e38f, -3.0e38f}, lrun[2] = {0.f, 0.f};
  u16* spb[2] = { sp8, sp8 + 1152 };
  const int wslice = ch*2048 + wid*256;

  #pragma unroll
  for (int kt = 0; kt < 4; ++kt){
    const int tb = wslice + kt*64;
    const u16* kb = Kb + (size_t)tb*64;
    const u16* vb = Vc + (size_t)(tb>>8)*48*256 + (tb & 255);
    short8v kf[4][2], vf[2][3];
    #pragma unroll
    for (int nt = 0; nt < 4; ++nt)
      #pragma unroll
      for (int kc = 0; kc < 2; ++kc)
        kf[nt][kc] = *(const short8v*)&kb[(nt*16+ln)*64 + kc*32 + qd*8];
    #pragma unroll
    for (int kc = 0; kc < 2; ++kc)
      #pragma unroll
      for (int dt = 0; dt < 3; ++dt)
        vf[kc][dt] = *(const short8v*)&vb[(dt*16+ln)*256 + kc*32 + qd*8];
    f32x4 s[2][4];
    #pragma unroll
    for (int rt = 0; rt < 2; ++rt)
      #pragma unroll
      for (int nt = 0; nt < 4; ++nt){
        f32x4 z = zf;
        z = __builtin_amdgcn_mfma_f32_16x16x32_bf16(kf[nt][0], aq[rt][0], z, 0,0,0);
        z = __builtin_amdgcn_mfma_f32_16x16x32_bf16(kf[nt][1], aq[rt][1], z, 0,0,0);
        s[rt][nt] = z;
      }
    #pragma unroll
    for (int rt = 0; rt < 2; ++rt){
      float vmax = fmaxf(fmaxf(fmaxf(s[rt][0][0], s[rt][0][1]), fmaxf(s[rt][0][2], s[rt][0][3])),
                   fmaxf(fmaxf(s[rt][1][0], s[rt][1][1]), fmaxf(s[rt][1][2], s[rt][1][3])));
      vmax = fmaxf(vmax, fmaxf(fmaxf(fmaxf(s[rt][2][0], s[rt][2][1]), fmaxf(s[rt][2][2], s[rt][2][3])),
                   fmaxf(fmaxf(s[rt][3][0], s[rt][3][1]), fmaxf(s[rt][3][2], s[rt][3][3]))));
      vmax = fmaxf(vmax, __shfl_xor(vmax, 16));
      vmax = fmaxf(vmax, __shfl_xor(vmax, 32));
      float mnew = fmaxf(mrun[rt], vmax);
      float alpha = exp2f(mrun[rt] - mnew);
      mrun[rt] = mnew;
      u16* sp = spb[rt];
      float lsum = 0.f;
      #pragma unroll
      for (int nt = 0; nt < 4; ++nt){
        float p0 = exp2f(s[rt][nt][0]-mnew), p1 = exp2f(s[rt][nt][1]-mnew);
        float p2 = exp2f(s[rt][nt][2]-mnew), p3 = exp2f(s[rt][nt][3]-mnew);
        lsum += (p0+p1)+(p2+p3);
        uint2 pk; pk.x = pk2(p0,p1); pk.y = pk2(p2,p3);
        *(uint2*)&sp[ln*72 + nt*16 + qd*4] = pk;
      }
      lsum += __shfl_xor(lsum, 16);
      lsum += __shfl_xor(lsum, 32);
      lrun[rt] = lrun[rt]*alpha + lsum;
      #pragma unroll
      for (int dt = 0; dt < 3; ++dt){
        acc[rt][dt][0] *= alpha; acc[rt][dt][1] *= alpha;
        acc[rt][dt][2] *= alpha; acc[rt][dt][3] *= alpha;
      }
      short8v pb0 = *(const short8v*)&sp[ln*72 + qd*8];
      short8v pb1 = *(const short8v*)&sp[ln*72 + 32 + qd*8];
      #pragma unroll
      for (int dt = 0; dt < 3; ++dt){
        acc[rt][dt] = __builtin_amdgcn_mfma_f32_16x16x32_bf16(vf[0][dt], pb0, acc[rt][dt], 0,0,0);
        acc[rt][dt] = __builtin_amdgcn_mfma_f32_16x16x32_bf16(vf[1][dt], pb1, acc[rt][dt], 0,0,0);
      }
    }
  }
  // ---- 8-wave merge -> one partial per (row, chunk), slab layout ----
  __syncthreads();
  float* sMg = (float*)SMEM;
  #pragma unroll
  for (int rt = 0; rt < 2; ++rt)
    #pragma unroll
    for (int dt = 0; dt < 3; ++dt)
      #pragma unroll
      for (int r = 0; r < 4; ++r)
        sMg[wid*1600 + (rt*16+ln)*50 + dt*16 + qd*4 + r] = acc[rt][dt][r];
  if (lane < 16){
    sMg[wid*1600 + ln*50 + 48] = mrun[0]; sMg[wid*1600 + ln*50 + 49] = lrun[0];
    sMg[wid*1600 + (16+ln)*50 + 48] = mrun[1]; sMg[wid*1600 + (16+ln)*50 + 49] = lrun[1];
  }
  __syncthreads();
  {
    int row = tid>>4, jj = tid&15, grow = rowbase + row;
    float mg = -3.0e38f, mv[8];
    #pragma unroll
    for (int w = 0; w < 8; ++w){ mv[w] = sMg[w*1600 + row*50 + 48]; mg = fmaxf(mg, mv[w]); }
    float ev[8], lg = 0.f;
    #pragma unroll
    for (int w = 0; w < 8; ++w){ ev[w] = exp2f(mv[w]-mg); lg += ev[w]*sMg[w*1600 + row*50 + 49]; }
    if (jj == 0){ mC[grow*16 + ch] = mg; lC[grow*16 + ch] = lg; }
    int d0 = jj*3;
    #pragma unroll
    for (int d3 = 0; d3 < 3; ++d3){
      int d = d0 + d3;
      float s = 0.f;
      #pragma unroll
      for (int w = 0; w < 8; ++w) s += ev[w]*sMg[w*1600 + row*50 + d];
      aC[((size_t)ch*512 + grow)*48 + d] = s;
    }
  }
}

// ---------------------------------------------------------------------------
// decoder: 12-step GRU(96); 640 blocks x 384 thr (6 waves); gates split 6-way
// (one 16-dim slice per wave, 3 ntiles each, frags in VGPRs); 15 waves/CU.
__global__ __launch_bounds__(384) void dec_kernel(
    const u16* Dihf, const u16* Dhhf, const float* b_ih, const float* b_hh,
    const float* stateP, const float* pred, const float* obs,
    const float* mF, const float* lF, const float* aF,
    const float* fc_w, const float* fc_b, float* out)
{
  __shared__ __align__(16) u16 sx[2][16*104];
  __shared__ float sPx[2][6][16], sPy[2][6][16];
  const int tid = threadIdx.x, bx = blockIdx.x;
  const int wid = tid>>6, lane = tid&63, qd = lane>>4, ln = lane&15;
  const int rw = bx*16;
  f32x4 zf = {0.f,0.f,0.f,0.f};

  for (int i = tid; i < 1536; i += 384){
    int r = i/96, k = i - r*96;
    int row = rw + r, b20 = row/20;
    float v = (k < 48) ? stateP[b20*48 + k] : pred[(size_t)row*48 + (k-48)];
    sx[0][r*104 + k] = f2bf(v);
  }
  if (tid < 48){
    int r19 = (19 - (rw % 20)) % 20;
    if (r19 < 16){
      int b = (rw + r19)/20;
      float mg = -3.0e38f, mv[16];
      #pragma unroll
      for (int c = 0; c < 16; ++c){ mv[c] = mF[b*16 + c]; mg = fmaxf(mg, mv[c]); }
      float num = 0.f, den = 0.f;
      #pragma unroll
      for (int c = 0; c < 16; ++c){
        float w = exp2f(mv[c] - mg);
        den += w * lF[b*16 + c];
        num += w * aF[((size_t)c*512 + b)*48 + tid];
      }
      sx[0][r19*104 + 48 + tid] = f2bf(num/den);
    }
  }
  // per-wave Dhh fragments: gates r,z,n -> ntiles wid, 6+wid, 12+wid
  short8v whh[3][3];
  #pragma unroll
  for (int g = 0; g < 3; ++g)
    #pragma unroll
    for (int kc = 0; kc < 3; ++kc)
      whh[g][kc] = *(const short8v*)&Dhhf[(((g*6+wid)*3+kc)*4+qd)*128 + ln*8];
  const int d = wid*16 + ln;
  float biR=b_ih[d], biZ=b_ih[96+d], biN=b_ih[192+d];
  float bhR=b_hh[d], bhZ=b_hh[96+d], bhN=b_hh[192+d];
  float fw0=fc_w[d], fw1=fc_w[96+d];
  float hold[4] = {0.f,0.f,0.f,0.f};
  float fcb0 = fc_b[0], fcb1 = fc_b[1];
  float pres0 = 0.f, pres1 = 0.f;
  if (wid == 0 && lane < 16){
    int b20 = (rw + lane)/20;
    pres0 = obs[b20*16 + 14];
    pres1 = obs[b20*16 + 15];
  }
  __syncthreads();

  #pragma unroll 1
  for (int t = 0; t < 12; ++t){
    const u16* sr = sx[t&1];
    u16* sw = sx[(t+1)&1];
    short8v xa0 = *(const short8v*)&sr[ln*104 + qd*8];
    short8v xa1 = *(const short8v*)&sr[ln*104 + 32 + qd*8];
    short8v xa2 = *(const short8v*)&sr[ln*104 + 64 + qd*8];
    f32x4 acc[3] = {zf, zf, zf};
    if (t == 0){
      #pragma unroll
      for (int g = 0; g < 3; ++g){
        int nt = g*6 + wid;
        acc[g] = __builtin_amdgcn_mfma_f32_16x16x32_bf16(xa0, *(const short8v*)&Dihf[((nt*3+0)*4+qd)*128 + ln*8], acc[g], 0,0,0);
        acc[g] = __builtin_amdgcn_mfma_f32_16x16x32_bf16(xa1, *(const short8v*)&Dihf[((nt*3+1)*4+qd)*128 + ln*8], acc[g], 0,0,0);
        acc[g] = __builtin_amdgcn_mfma_f32_16x16x32_bf16(xa2, *(const short8v*)&Dihf[((nt*3+2)*4+qd)*128 + ln*8], acc[g], 0,0,0);
      }
    } else {
      #pragma unroll
      for (int g = 0; g < 3; ++g){
        acc[g] = __builtin_amdgcn_mfma_f32_16x16x32_bf16(xa0, whh[g][0], acc[g], 0,0,0);
        acc[g] = __builtin_amdgcn_mfma_f32_16x16x32_bf16(xa1, whh[g][1], acc[g], 0,0,0);
        acc[g] = __builtin_amdgcn_mfma_f32_16x16x32_bf16(xa2, whh[g][2], acc[g], 0,0,0);
      }
    }
    float px[4], py[4];
    #pragma unroll
    for (int r = 0; r < 4; ++r){
      float rr = sigm(acc[0][r] + biR + bhR);
      float zz = sigm(acc[1][r] + biZ + bhZ);
      float nn = (t == 0) ? tanh_fast(acc[2][r] + biN + rr*bhN)
                          : tanh_fast(biN + rr*(acc[2][r] + bhN));
      float hv = (1.f-zz)*nn + zz*hold[r];
      hold[r] = hv;
      sw[(qd*4+r)*104 + d] = f2bf(hv);
      px[r] = fw0*hv;
      py[r] = fw1*hv;
    }
    #pragma unroll
    for (int msk = 8; msk >= 1; msk >>= 1)
      #pragma unroll
      for (int r = 0; r < 4; ++r){
        px[r] += __shfl_xor(px[r], msk);
        py[r] += __shfl_xor(py[r], msk);
      }
    if (ln == 0){
      #pragma unroll
      for (int r = 0; r < 4; ++r){
        sPx[t&1][wid][qd*4+r] = px[r];
        sPy[t&1][wid][qd*4+r] = py[r];
      }
    }
    __syncthreads();
    if (wid == 0 && lane < 16){
      float fx = 0.f, fy = 0.f;
      #pragma unroll
      for (int w = 0; w < 6; ++w){ fx += sPx[t&1][w][lane]; fy += sPy[t&1][w][lane]; }
      pres0 += fx + fcb0;
      pres1 += fy + fcb1;
      out[((size_t)(rw + lane)*12 + t)*2 + 0] = pres0;
      out[((size_t)(rw + lane)*12 + t)*2 + 1] = pres1;
    }
  }
}

// ---------------------------------------------------------------------------
extern "C" void kernel_launch(void* const* d_in, const int* in_sizes, int n_in,
                              void* d_out, int out_size, void* d_ws, size_t ws_size,
                              hipStream_t stream)
{
  const float* past        = (const float*)d_in[0];
  const float* obs         = (const float*)d_in[1];
  const float* conv_w      = (const float*)d_in[2];
  const float* conv_b      = (const float*)d_in[3];
  const float* enc_w_ih    = (const float*)d_in[4];
  const float* enc_w_hh    = (const float*)d_in[5];
  const float* enc_b_ih    = (const float*)d_in[6];
  const float* enc_b_hh    = (const float*)d_in[7];
  const float* memory_past = (const float*)d_in[8];
  const float* memory_fut  = (const float*)d_in[9];
  const float* Wq = (const float*)d_in[10];
  const float* bq = (const float*)d_in[11];
  const float* Wk = (const float*)d_in[12];
  const float* bk = (const float*)d_in[13];
  const float* Wv = (const float*)d_in[14];
  const float* bv = (const float*)d_in[15];
  const float* dec_w_ih = (const float*)d_in[16];
  const float* dec_w_hh = (const float*)d_in[17];
  const float* dec_b_ih = (const float*)d_in[18];
  const float* dec_b_hh = (const float*)d_in[19];
  const float* fc_w = (const float*)d_in[20];
  const float* fc_b = (const float*)d_in[21];
  float* out = (float*)d_out;

  char* ws = (char*)d_ws;
  size_t off = 0;
  auto alloc = [&](size_t bytes){ void* p = ws + off; off += (bytes + 255) & ~(size_t)255; return p; };
  float* stateP = (float*)alloc(512*48*4);
  float* qfA    = (float*)alloc(512*48*4);
  float* qfB    = (float*)alloc(512*48*4);
  u16*   qbB    = (u16*)alloc(512*64*2);
  float* mB[2], *lB[2], *aB[2];
  for (int i = 0; i < 2; ++i){
    mB[i] = (float*)alloc(512*16*4);
    lB[i] = (float*)alloc(512*16*4);
    aB[i] = (float*)alloc((size_t)512*16*48*4);
  }
  float* pred = (float*)alloc((size_t)10240*48*4);
  u16*   Kb   = (u16*)alloc((size_t)32768*64*2);
  u16*   Vc   = (u16*)alloc((size_t)32768*48*2);
  u16*   Dihf = (u16*)alloc(27648*2);
  u16*   Dhhf = (u16*)alloc(27648*2);
  u16*   EihF = (u16*)alloc(9216*2);
  u16*   EhhF = (u16*)alloc(9216*2);
  u16*   WqF  = (u16*)alloc(3072*2);
  u16*   WkF  = (u16*)alloc(3072*2);
  u16*   WvF  = (u16*)alloc(3072*2);
  float* qbuf[2] = { qfA, qfB };

  prep_kernel<<<324, 256, 0, stream>>>(dec_w_ih, dec_w_hh, enc_w_ih, enc_w_hh,
                                       Wq, Wk, Wv, Dihf, Dhhf, EihF, EhhF, WqF, WkF, WvF);

  setup_kernel<<<512, 256, 0, stream>>>(
      past, conv_w, conv_b, enc_b_ih, enc_b_hh, memory_past, memory_fut,
      bq, bk, bv, EihF, EhhF, WqF, WkF, WvF,
      stateP, qfA, qbB, Kb, Vc);

  iter_kernel<<<256, 512, 0, stream>>>(0, 0, qbB, Kb, Vc, WqF, bq,
      qfA, qfA, pred, mB[1], lB[1], aB[1], mB[0], lB[0], aB[0]);
  for (int it = 1; it < 20; ++it){
    int pv = (it-1)&1, cu = it&1;
    iter_kernel<<<256, 512, 0, stream>>>(1, it, qbB, Kb, Vc, WqF, bq,
        qbuf[pv], qbuf[cu], pred, mB[pv], lB[pv], aB[pv], mB[cu], lB[cu], aB[cu]);
  }

  // it=19 wrote buffer index 1 -> dec consumes mB[1]/lB[1]/aB[1]
  dec_kernel<<<640, 384, 0, stream>>>(Dihf, Dhhf, dec_b_ih, dec_b_hh,
      stateP, pred, obs, mB[1], lB[1], aB[1], fc_w, fc_b, out);
}